// Round 13
// baseline (467.071 us; speedup 1.0000x reference)
//
#include <hip/hip_runtime.h>
#include <hip/hip_bf16.h>

#define T_LEN 200
#define F_IN 64
#define A_IN 128
#define H 100
#define H4 400
#define OUT_N 10
#define ROWS 8
#define NTHR 256

typedef __attribute__((ext_vector_type(8))) short bf16x8;
typedef __attribute__((ext_vector_type(4))) float f32x4;

#define NLOG2E -1.4426950408889634f

__device__ __forceinline__ unsigned short f2bf(float f) {
    union { float f; unsigned u; } v; v.f = f;
    unsigned r = v.u + 0x7FFFu + ((v.u >> 16) & 1u);
    return (unsigned short)(r >> 16);
}

__device__ __forceinline__ unsigned cvtpk(float lo, float hi) {
    unsigned r;
    asm("v_cvt_pk_bf16_f32 %0, %1, %2" : "=v"(r) : "v"(lo), "v"(hi));
    return r;
}

// sigmoid(z) where zp = -log2(e)*z came out of the MFMA (weights pre-scaled)
__device__ __forceinline__ float sigm2(float zp) {
    return __builtin_amdgcn_rcpf(1.0f + __builtin_amdgcn_exp2f(zp));
}

// LDS-only barrier: do NOT drain vmcnt (seq prefetch stays in flight)
__device__ __forceinline__ void lds_barrier() {
    asm volatile("s_waitcnt lgkmcnt(0)" ::: "memory");
    __builtin_amdgcn_s_barrier();
}

// h fragment slot for (batch b, hidden j): B-frag col=lane&15=b, k=lg*8+i
#define HOFF(b, j) ((((j) >> 5) * 64 + ((b) + 16 * (((j) >> 3) & 3))) * 8 + ((j) & 7))

extern "C" __global__ void __launch_bounds__(NTHR)
traj_kernel(const float* __restrict__ attrs, const float* __restrict__ seq,
            const float* __restrict__ Wd, const float* __restrict__ bd,
            const float* __restrict__ Wk, const float* __restrict__ Wr,
            const float* __restrict__ bl, const float* __restrict__ W1,
            const float* __restrict__ b1, const float* __restrict__ W2,
            const float* __restrict__ b2, const float* __restrict__ Wc,
            const float* __restrict__ bc, float* __restrict__ out)
{
    // LDS map (bytes), total 25344 (x2 blocks/CU = 50.7 KB <= 160 KB):
    //   [0, 8192)        hl    ushort[2][2048]  h bf16 B-frag double buffer
    //   [16000, 19200)   h32   float[8][100]    final h fp32 (filled post-loop)
    //   [19200, 21248)   wk24  Wk A-frags tile 24 (wave-3-private)
    //   [21248, 25344)   wr24  Wr A-frags tile 24 (wave-3-private)
    // epilogue aliases in [0,16000) (hl dead after h32 fill): att [8][136]@0,
    //   catb [8][204]@4352, x1b [8][100]@10880, x2b [8][50]@14080, lgb [8][10]@15680
    __shared__ __align__(16) char smem[25344];
    unsigned short* hl = (unsigned short*)smem;
    float* h32 = (float*)(smem + 16000);

    const int tid = threadIdx.x;
    const int lane = tid & 63;
    const int w = tid >> 6;            // 4 waves (1 per SIMD)
    const int ln15 = lane & 15;
    const int lg = lane >> 4;
    const int b0 = blockIdx.x * ROWS;

    // tiles: wave w owns {6w .. 6w+5} in registers; wave 3 also tile 24 via LDS
    const int nt0 = 6 * w;
    const bool w3 = (w == 3);

    // A-frag: lane holds row m=lane&15, k=(lane>>4)*8+i. Permuted row p=tile*16+m
    // -> original column c=(tile*4+(m>>2))+100*(m&3); D rows lg*4+r = gates i,f,g,o
    // of hidden j=tile*4+lg. Gates i,f,o pre-scaled by -log2(e) for exp2 sigmoid.
    const int rw = ln15 & 3;
    const int qr = ln15 >> 2;
    const float gsc = (rw == 2) ? 1.0f : NLOG2E;

    // ---- Wk frags in registers (6 tiles) ----
    bf16x8 wkf[6][2];
#pragma unroll
    for (int q = 0; q < 6; q++) {
        const int c = ((nt0 + q) * 4 + qr) + 100 * rw;
#pragma unroll
        for (int kt = 0; kt < 2; kt++) {
            bf16x8 f;
#pragma unroll
            for (int i = 0; i < 8; i++) {
                int k = kt * 32 + lg * 8 + i;
                f[i] = (short)f2bf(gsc * Wk[k * H4 + c]);
            }
            wkf[q][kt] = f;
        }
    }

    // ---- Wr frags in registers (6 tiles), bias folded into spare K-row k==100 ----
    bf16x8 wrf[6][4];
#pragma unroll
    for (int q = 0; q < 6; q++) {
        const int c = ((nt0 + q) * 4 + qr) + 100 * rw;
#pragma unroll
        for (int kt = 0; kt < 4; kt++) {
            bf16x8 f;
#pragma unroll
            for (int i = 0; i < 8; i++) {
                int k = kt * 32 + lg * 8 + i;
                float x = 0.0f;
                if (k < H) x = gsc * Wr[k * H4 + c];
                if (k == H) x = gsc * bl[c];   // bias row (h slot k=100 pinned to 1)
                f[i] = (short)f2bf(x);
            }
            wrf[q][kt] = f;
        }
    }

    // ---- wave 3: tile-24 Wk+Wr frags -> wave-private LDS ----
    if (w3) {
        const int c = (24 * 4 + qr) + 100 * rw;
#pragma unroll
        for (int kt = 0; kt < 2; kt++) {
            bf16x8 f;
#pragma unroll
            for (int i = 0; i < 8; i++) {
                int k = kt * 32 + lg * 8 + i;
                f[i] = (short)f2bf(gsc * Wk[k * H4 + c]);
            }
            *(bf16x8*)(smem + 19200 + kt * 1024 + lane * 16) = f;
        }
#pragma unroll
        for (int kt = 0; kt < 4; kt++) {
            bf16x8 f;
#pragma unroll
            for (int i = 0; i < 8; i++) {
                int k = kt * 32 + lg * 8 + i;
                float x = 0.0f;
                if (k < H) x = gsc * Wr[k * H4 + c];
                if (k == H) x = gsc * bl[c];
                f[i] = (short)f2bf(x);
            }
            *(bf16x8*)(smem + 21248 + kt * 1024 + lane * 16) = f;
        }
    }

    // gate destinations: batch b = ln15 (8..15 confined garbage), hidden j
    int hoq[6];
#pragma unroll
    for (int q = 0; q < 6; q++) hoq[q] = HOFF(ln15, (nt0 + q) * 4 + lg);
    const int ho6 = HOFF(ln15, 96 + lg);    // w3's tile 24
    float cr[6];
#pragma unroll
    for (int q = 0; q < 6; q++) cr[q] = 0.f;
    float cr6 = 0.f;

    // zero both h buffers, then pin bias slot k=100 to bf16(1.0) in both
    for (int i = tid; i < 4096; i += NTHR) hl[i] = 0;
    __syncthreads();
    if (tid < 32) {
        int b = tid & 15, buf = tid >> 4;
        hl[buf * 2048 + 1536 + 8 * b + 4] = 0x3F80;  // (k=100, batch b) = 1.0
    }

    // ---- seq staging: lane = batch row ln15 (clamped), feats lg*8..+7, 32+lg*8..+7
    int brow = b0 + ln15; if (brow > 4095) brow = 4095;
    const float* sp = seq + (size_t)brow * (T_LEN * F_IN) + lg * 8;
    f32x4 s0 = *(const f32x4*)(sp);
    f32x4 s1 = *(const f32x4*)(sp + 4);
    f32x4 s2 = *(const f32x4*)(sp + 32);
    f32x4 s3 = *(const f32x4*)(sp + 36);
    sp += F_IN;

    const char* wk24p = smem + 19200 + lane * 16;
    const char* wr24p = smem + 21248 + lane * 16;
    f32x4 accX[6]; f32x4 accX6;

    // prologue: accX = x(0)@Wk^T (C=0; bias arrives via Wr kt=3 each step)
    {
        union { unsigned u[4]; bf16x8 v; } ua, ub;
        ua.u[0] = cvtpk(s0[0], s0[1]); ua.u[1] = cvtpk(s0[2], s0[3]);
        ua.u[2] = cvtpk(s1[0], s1[1]); ua.u[3] = cvtpk(s1[2], s1[3]);
        ub.u[0] = cvtpk(s2[0], s2[1]); ub.u[1] = cvtpk(s2[2], s2[3]);
        ub.u[2] = cvtpk(s3[0], s3[1]); ub.u[3] = cvtpk(s3[2], s3[3]);
        bf16x8 a0 = ua.v, a1 = ub.v;
        const f32x4 zz = { 0.f, 0.f, 0.f, 0.f };
#pragma unroll
        for (int q = 0; q < 6; q++) {
            f32x4 x = __builtin_amdgcn_mfma_f32_16x16x32_bf16(wkf[q][0], a0, zz, 0, 0, 0);
            accX[q] = __builtin_amdgcn_mfma_f32_16x16x32_bf16(wkf[q][1], a1, x, 0, 0, 0);
        }
        if (w3) {
            bf16x8 wa = *(const bf16x8*)(wk24p);
            bf16x8 wb = *(const bf16x8*)(wk24p + 1024);
            f32x4 x = __builtin_amdgcn_mfma_f32_16x16x32_bf16(wa, a0, zz, 0, 0, 0);
            accX6 = __builtin_amdgcn_mfma_f32_16x16x32_bf16(wb, a1, x, 0, 0, 0);
        }
    }
    // issue load of x(1)
    s0 = *(const f32x4*)(sp);
    s1 = *(const f32x4*)(sp + 4);
    s2 = *(const f32x4*)(sp + 32);
    s3 = *(const f32x4*)(sp + 36);
    sp += F_IN;

    lds_barrier();   // hl zeros + bias pins visible (seq loads stay in flight)

#pragma unroll 2
    for (int t = 0; t < T_LEN; t++) {
        const bool notlast = (t < T_LEN - 1);
        const bool even = ((t & 1) == 0);

        // ---- read h(t-1) B-frags from parity buffer; w3 also tile-24 Wr frags ----
        const unsigned short* hp = hl + (even ? 0 : 2048) + lane * 8;
        bf16x8 hf0 = *(const bf16x8*)(hp);
        bf16x8 hf1 = *(const bf16x8*)(hp + 512);
        bf16x8 hf2 = *(const bf16x8*)(hp + 1024);
        bf16x8 hf3 = *(const bf16x8*)(hp + 1536);
        bf16x8 w40, w41, w42, w43;
        if (w3) {
            w40 = *(const bf16x8*)(wr24p);
            w41 = *(const bf16x8*)(wr24p + 1024);
            w42 = *(const bf16x8*)(wr24p + 2048);
            w43 = *(const bf16x8*)(wr24p + 3072);
        }

        // cvt x(t+1) (overlaps LDS read latency)
        bf16x8 a0n = {}, a1n = {};
        if (notlast) {
            union { unsigned u[4]; bf16x8 v; } ua, ub;
            ua.u[0] = cvtpk(s0[0], s0[1]); ua.u[1] = cvtpk(s0[2], s0[3]);
            ua.u[2] = cvtpk(s1[0], s1[1]); ua.u[3] = cvtpk(s1[2], s1[3]);
            ub.u[0] = cvtpk(s2[0], s2[1]); ub.u[1] = cvtpk(s2[2], s2[3]);
            ub.u[2] = cvtpk(s3[0], s3[1]); ub.u[3] = cvtpk(s3[2], s3[3]);
            a0n = ua.v; a1n = ub.v;
        }

        // ---- accX += h(t-1)@Wr^T in place (+bias via kt=3); kt-major, 6-7-way ILP ----
        __builtin_amdgcn_s_setprio(1);
#pragma unroll
        for (int q = 0; q < 6; q++)
            accX[q] = __builtin_amdgcn_mfma_f32_16x16x32_bf16(wrf[q][0], hf0, accX[q], 0, 0, 0);
        if (w3) accX6 = __builtin_amdgcn_mfma_f32_16x16x32_bf16(w40, hf0, accX6, 0, 0, 0);
#pragma unroll
        for (int q = 0; q < 6; q++)
            accX[q] = __builtin_amdgcn_mfma_f32_16x16x32_bf16(wrf[q][1], hf1, accX[q], 0, 0, 0);
        if (w3) accX6 = __builtin_amdgcn_mfma_f32_16x16x32_bf16(w41, hf1, accX6, 0, 0, 0);
#pragma unroll
        for (int q = 0; q < 6; q++)
            accX[q] = __builtin_amdgcn_mfma_f32_16x16x32_bf16(wrf[q][2], hf2, accX[q], 0, 0, 0);
        if (w3) accX6 = __builtin_amdgcn_mfma_f32_16x16x32_bf16(w42, hf2, accX6, 0, 0, 0);
#pragma unroll
        for (int q = 0; q < 6; q++)
            accX[q] = __builtin_amdgcn_mfma_f32_16x16x32_bf16(wrf[q][3], hf3, accX[q], 0, 0, 0);
        if (w3) accX6 = __builtin_amdgcn_mfma_f32_16x16x32_bf16(w43, hf3, accX6, 0, 0, 0);
        __builtin_amdgcn_s_setprio(0);

        // prefetch x(t+2) (rides across the LDS barrier)
        if (t < T_LEN - 2) {
            s0 = *(const f32x4*)(sp);
            s1 = *(const f32x4*)(sp + 4);
            s2 = *(const f32x4*)(sp + 32);
            s3 = *(const f32x4*)(sp + 36);
            sp += F_IN;
        }

        // ---- gates in registers; write h(t) bf16 to parity buffer ----
        unsigned short* hwp = hl + (even ? 2048 : 0);

#define DOGATE(AX, CR, HO) do {                                        \
            float _i = sigm2(AX[0]), _f = sigm2(AX[1]);                \
            float _g = fmaxf(AX[2], 0.0f), _o = sigm2(AX[3]);          \
            CR = _f * CR + _i * _g;                                    \
            float _h = _o * fmaxf(CR, 0.0f);                           \
            hwp[HO] = (unsigned short)cvtpk(_h, _h);                   \
        } while (0)

#pragma unroll
        for (int q = 0; q < 6; q++) DOGATE(accX[q], cr[q], hoq[q]);
        if (w3) DOGATE(accX6, cr6, ho6);

        // ---- accX = x(t+1)@Wk^T (MFMA pipe, overlaps gate VALU) ----
        if (notlast) {
            const f32x4 zz = { 0.f, 0.f, 0.f, 0.f };
#pragma unroll
            for (int q = 0; q < 6; q++) {
                f32x4 x = __builtin_amdgcn_mfma_f32_16x16x32_bf16(wkf[q][0], a0n, zz, 0, 0, 0);
                accX[q] = __builtin_amdgcn_mfma_f32_16x16x32_bf16(wkf[q][1], a1n, x, 0, 0, 0);
            }
            if (w3) {
                bf16x8 wa = *(const bf16x8*)(wk24p);
                bf16x8 wb = *(const bf16x8*)(wk24p + 1024);
                f32x4 x = __builtin_amdgcn_mfma_f32_16x16x32_bf16(wa, a0n, zz, 0, 0, 0);
                accX6 = __builtin_amdgcn_mfma_f32_16x16x32_bf16(wb, a1n, x, 0, 0, 0);
            }
        }

        lds_barrier();   // h(t) visible; protects buf WAR; vmem stays in flight
    }

    // ---- final h -> h32 from hl buf0 (t=199 wrote buf[(199+1)&1] = buf0) ----
    for (int idx = tid; idx < ROWS * H; idx += NTHR) {
        int b = idx & 7, j = idx >> 3;
        union { unsigned u; float f; } cv;
        cv.u = ((unsigned)hl[HOFF(b, j)]) << 16;
        h32[b * H + j] = cv.f;
    }
    __syncthreads();   // h32 ready; hl dead -> epilogue may overlay

    // ---- epilogue: fp32 dense chain + softmax (ROWS=8, 256 threads) ----
    float* att  = (float*)smem;            // [8][136]
    float* catb = (float*)(smem + 4352);   // [8][204]
    float* x1b  = (float*)(smem + 10880);  // [8][100]
    float* x2b  = (float*)(smem + 14080);  // [8][50]
    float* lgb  = (float*)(smem + 15680);  // [8][10]

    {
        f32x4 v = ((const f32x4*)(attrs + (size_t)b0 * A_IN))[tid];  // 8x128 floats
        int row = tid >> 5, c4 = tid & 31;
        *(f32x4*)(att + row * 136 + c4 * 4) = v;
    }
    __syncthreads();

#pragma unroll
    for (int k = 0; k < 4; k++) {
        int e = tid + NTHR * k;
        if (e < ROWS * H) {
            int b = e & 7, j = e >> 3;
            float s = bd[j];
            for (int kk = 0; kk < A_IN; kk++) s += att[b * 136 + kk] * Wd[kk * H + j];
            catb[b * 204 + j] = fmaxf(s, 0.0f);
            catb[b * 204 + H + j] = h32[b * H + j];
        }
    }
    __syncthreads();

#pragma unroll
    for (int k = 0; k < 4; k++) {
        int e = tid + NTHR * k;
        if (e < ROWS * H) {
            int b = e & 7, j = e >> 3;
            float s = b1[j];
            for (int kk = 0; kk < 200; kk++) s += catb[b * 204 + kk] * W1[kk * H + j];
            x1b[b * H + j] = fmaxf(s, 0.0f);
        }
    }
    __syncthreads();

#pragma unroll
    for (int k = 0; k < 2; k++) {
        int e = tid + NTHR * k;
        if (e < ROWS * 50) {
            int b = e & 7, j = e >> 3;
            float s = b2[j];
            for (int kk = 0; kk < H; kk++) s += x1b[b * H + kk] * W2[kk * 50 + j];
            x2b[b * 50 + j] = fmaxf(s, 0.0f);
        }
    }
    __syncthreads();

    if (tid < ROWS * OUT_N) {
        int b = tid / OUT_N, o = tid % OUT_N;
        float s = bc[o];
        for (int kk = 0; kk < 50; kk++) s += x2b[b * 50 + kk] * Wc[kk * OUT_N + o];
        lgb[b * OUT_N + o] = s;
    }
    __syncthreads();

    if (tid < ROWS) {
        int b = tid;
        float m = -1e30f, v[10];
#pragma unroll
        for (int o = 0; o < 10; o++) { v[o] = lgb[b * 10 + o]; m = fmaxf(m, v[o]); }
        float ssum = 0.0f;
#pragma unroll
        for (int o = 0; o < 10; o++) { v[o] = __expf(v[o] - m); ssum += v[o]; }
        float inv = 1.0f / ssum;
#pragma unroll
        for (int o = 0; o < 10; o++) out[(size_t)(b0 + b) * 10 + o] = v[o] * inv;
    }
}

extern "C" void kernel_launch(void* const* d_in, const int* in_sizes, int n_in,
                              void* d_out, int out_size, void* d_ws, size_t ws_size,
                              hipStream_t stream) {
    const float* attrs = (const float*)d_in[0];
    const float* seq   = (const float*)d_in[1];
    const float* Wd    = (const float*)d_in[2];
    const float* bd    = (const float*)d_in[3];
    const float* Wk    = (const float*)d_in[4];
    const float* Wr    = (const float*)d_in[5];
    const float* bl    = (const float*)d_in[6];
    const float* W1    = (const float*)d_in[7];
    const float* b1    = (const float*)d_in[8];
    const float* W2    = (const float*)d_in[9];
    const float* b2    = (const float*)d_in[10];
    const float* Wc    = (const float*)d_in[11];
    const float* bc    = (const float*)d_in[12];
    float* out = (float*)d_out;

    hipLaunchKernelGGL(traj_kernel, dim3(512), dim3(NTHR), 0, stream,
                       attrs, seq, Wd, bd, Wk, Wr, bl, W1, b1, W2, b2, Wc, bc, out);
}